// Round 4
// baseline (7866.521 us; speedup 1.0000x reference)
//
#include <hip/hip_runtime.h>
#include <cstdint>
#include <cstddef>

// ============================================================================
// 4-layer LSTM (B=128, T=1024, D=128, H={100,100,200,200}) + linear head.
// R11 = R9 (best, 6474us) + sync-protocol cost reduction:
//  - GROUP-SUM COUNTERS: one atomicAdd counter per (layer,group) replaces
//    P per-member flags. Progress spread within a group is provably <=1
//    (a member at t+1 needed all members' h_t), so Sum(prog) >= P*t is an
//    exact test for min(prog) >= t. Detection = ONE lane polling ONE line
//    (was: up-to-20-lane gather across 20 lines, >=1 RT per spin loop).
//  - OWN-FIRST ORDER: own-wait -> own-MFMA -> {upstream+backpressure fused
//    wait} -> x-MFMA. The upstream hop overlaps own compute instead of
//    sitting inside the self-recurrence loop.
//  - s_sleep(2) (finer detection granularity; poll traffic is now tiny).
// Load/MFMA structure is byte-identical to R9 (R10 showed batching loads
// into register arrays regresses: VGPR 48->100, VALUBusy 2x).
// ============================================================================

#define AGENT __HIP_MEMORY_SCOPE_AGENT
#define FSTR 64   // u32 stride between counters (256B sector each)

typedef __attribute__((ext_vector_type(8))) short  short8;
typedef __attribute__((ext_vector_type(4))) float  f32x4;

struct us4 { unsigned short x, y, z, w; };

__device__ __forceinline__ unsigned short f2bf(float x){
  unsigned u = __float_as_uint(x);
  unsigned r = u + 0x7FFFu + ((u >> 16) & 1u);   // RN-even to bf16
  return (unsigned short)(r >> 16);
}
__device__ __forceinline__ float bf2f(unsigned short h){
  return __uint_as_float(((unsigned)h) << 16);
}
__device__ __forceinline__ float sigmoidf_(float x){ return 1.f / (1.f + __expf(-x)); }
__device__ __forceinline__ float tanhf_(float x){
  // tanh(x) = 1 - 2/(1+e^{2x}); __expf saturates cleanly at both ends.
  return 1.f - 2.f / (1.f + __expf(2.f * x));
}

__device__ __forceinline__ void spin_ge(const unsigned* p, unsigned v){
  #pragma unroll 1
  for (int i = 0; i < 32; ++i){
    if (__hip_atomic_load(p, __ATOMIC_RELAXED, AGENT) >= v) return;
  }
  long s = 0;
  #pragma unroll 1
  while (__hip_atomic_load(p, __ATOMIC_RELAXED, AGENT) < v){
    __builtin_amdgcn_s_sleep(2);               // ~0.05us backoff
    if (++s > (1L << 19)) break;               // fail fast on true deadlock
  }
}

__device__ __forceinline__ void load_hx(const unsigned* base, int w32, int loOff,
                                        short8& ah, short8& al){
  union U { unsigned long long q[2]; short8 v; } uh, ul;
  const unsigned long long* ph = (const unsigned long long*)(base + w32);
  const unsigned long long* pl = (const unsigned long long*)(base + loOff + w32);
  uh.q[0] = __hip_atomic_load(ph + 0, __ATOMIC_RELAXED, AGENT);
  uh.q[1] = __hip_atomic_load(ph + 1, __ATOMIC_RELAXED, AGENT);
  ul.q[0] = __hip_atomic_load(pl + 0, __ATOMIC_RELAXED, AGENT);
  ul.q[1] = __hip_atomic_load(pl + 1, __ATOMIC_RELAXED, AGENT);
  ah = uh.v; al = ul.v;
}

// ---------------------------------------------------------------------------
// K1: pregate GEMM for layer 0 only.  G[m][n] = xs_row(m) @ Wx0 + b0.
// ---------------------------------------------------------------------------
__global__ __launch_bounds__(256) void gemm_pregate(
    const float* __restrict__ A, const float* __restrict__ W,
    const float* __restrict__ bias, float* __restrict__ G,
    int K, int KT, int N, size_t strideT, size_t strideB)
{
  __shared__ unsigned short Ahi[256*40];
  __shared__ unsigned short Alo[256*40];
  __shared__ unsigned short Bhi[80*40];
  __shared__ unsigned short Blo[80*40];

  const int tid  = threadIdx.x;
  const int mb   = blockIdx.x;
  const int n0   = blockIdx.y * 80;
  const int wave = tid >> 6, lane = tid & 63;
  const int ln15 = lane & 15, quad = lane >> 4;

  f32x4 acc[4][5];
  for (int a = 0; a < 4; ++a)
    for (int b = 0; b < 5; ++b)
      acc[a][b] = (f32x4){0.f, 0.f, 0.f, 0.f};

  for (int kt = 0; kt < KT; ++kt){
    const int k0 = kt * 32;
    const bool full = (k0 + 31) < K;
    for (int i = 0; i < 8; ++i){
      const int e   = tid + 256*i;
      const int row = e >> 3, seg = e & 7;
      const int mm  = mb*256 + row;
      const float* rp = A + (size_t)(mm >> 7)*strideT + (size_t)(mm & 127)*strideB;
      const int k = k0 + seg*4;
      float v0, v1, v2, v3;
      if (full){
        float4 v = *(const float4*)(rp + k);
        v0 = v.x; v1 = v.y; v2 = v.z; v3 = v.w;
      } else {
        v0 = (k+0 < K) ? rp[k+0] : 0.f;
        v1 = (k+1 < K) ? rp[k+1] : 0.f;
        v2 = (k+2 < K) ? rp[k+2] : 0.f;
        v3 = (k+3 < K) ? rp[k+3] : 0.f;
      }
      const unsigned short h0=f2bf(v0), h1=f2bf(v1), h2=f2bf(v2), h3=f2bf(v3);
      us4 hv{h0, h1, h2, h3};
      us4 lv{f2bf(v0-bf2f(h0)), f2bf(v1-bf2f(h1)), f2bf(v2-bf2f(h2)), f2bf(v3-bf2f(h3))};
      *(us4*)&Ahi[row*40 + seg*4] = hv;
      *(us4*)&Alo[row*40 + seg*4] = lv;
    }
    for (int i = 0; i < 10; ++i){
      const int e  = tid + 256*i;
      const int kk = e / 80, nn = e - kk*80;
      const int k  = k0 + kk;
      const float v = (k < K) ? W[(size_t)k*N + n0 + nn] : 0.f;
      const unsigned short hb = f2bf(v);
      Bhi[nn*40 + kk] = hb;
      Blo[nn*40 + kk] = f2bf(v - bf2f(hb));
    }
    __syncthreads();
    short8 a_h[4], a_l[4];
    for (int mt = 0; mt < 4; ++mt){
      const int aoff = (wave*64 + mt*16 + ln15)*40 + quad*8;
      a_h[mt] = *(const short8*)&Ahi[aoff];
      a_l[mt] = *(const short8*)&Alo[aoff];
    }
    for (int nt = 0; nt < 5; ++nt){
      const int boff = (nt*16 + ln15)*40 + quad*8;
      const short8 b_h = *(const short8*)&Bhi[boff];
      const short8 b_l = *(const short8*)&Blo[boff];
      for (int mt = 0; mt < 4; ++mt){
        acc[mt][nt] = __builtin_amdgcn_mfma_f32_16x16x32_bf16(a_h[mt], b_h, acc[mt][nt], 0,0,0);
        acc[mt][nt] = __builtin_amdgcn_mfma_f32_16x16x32_bf16(a_l[mt], b_h, acc[mt][nt], 0,0,0);
        acc[mt][nt] = __builtin_amdgcn_mfma_f32_16x16x32_bf16(a_h[mt], b_l, acc[mt][nt], 0,0,0);
      }
    }
    __syncthreads();
  }
  for (int nt = 0; nt < 5; ++nt){
    const float bv = bias[n0 + nt*16 + ln15];
    for (int mt = 0; mt < 4; ++mt){
      const int mbase = mb*256 + wave*64 + mt*16 + quad*4;
      #pragma unroll
      for (int r = 0; r < 4; ++r)
        G[(size_t)(mbase + r)*N + n0 + nt*16 + ln15] = acc[mt][nt][r] + bv;
    }
  }
}

// ---------------------------------------------------------------------------
// Fused pipeline stage (window-8 h slots, group-sum counters, own-first).
// Hx layout per layer: [slot(8)][group(8)][plane hi/lo][16 rows][RS u32].
// Counter per (layer,group): ctr[g*FSTR]; producer tid0 adds 1 per step.
// ---------------------------------------------------------------------------
template<int H, int HP, int P, bool HAS_X>
__device__ __forceinline__ void rec_stage(
    const float* __restrict__ G0, const float* __restrict__ Wx,
    const float* __restrict__ Wh, const float* __restrict__ bias,
    int HprevReal,
    const unsigned* __restrict__ HxUp, unsigned* __restrict__ HxOwn,
    const unsigned* __restrict__ ctrUp, unsigned* __restrict__ ctrOwn,
    const unsigned* __restrict__ ctrDn, int PUp, int PDn,
    float* __restrict__ cstate, float* __restrict__ hlast,
    int g, int m, int t0, int TC, int Tlast, char* smem)
{
  constexpr int HHM  = H / P;                 // 20
  constexpr int COLS = 4 * HHM;               // 80
  constexpr int CP   = COLS;
  constexpr int ZSTR = CP + 1;                // zbuf row stride (pad)
  constexpr int KPo  = ((H + 31)/32)*32;      // own-h padded K
  constexpr int RSo  = KPo / 2;               // own Hx row stride (u32)
  constexpr int RSp  = HP / 2;                // upstream Hx row stride
  constexpr int KX   = HAS_X ? HP : 0;
  constexpr int KALL = KX + KPo;
  constexpr int KTX  = KX / 32;
  constexpr int KTH  = KPo / 32;
  constexpr int KSTR = KALL + 8;
  constexpr int NT   = CP / 16;               // 5
  constexpr int NE   = 16 * HHM / 2;          // 160
  constexpr int PR   = HHM / 2;               // 10
  constexpr int N4H  = 4 * H;
  constexpr int SLOTo = 2*16*RSo;             // u32 per (slot,group), own
  constexpr int SLOTp = 2*16*RSp;             // u32 per (slot,group), upstream

  unsigned short* whT_hi = (unsigned short*)smem;
  unsigned short* whT_lo = whT_hi + CP*KSTR;
  float* zbuf = (float*)(whT_lo + CP*KSTR);   // [16][ZSTR]

  const int tid  = threadIdx.x;
  const int row0 = g * 16;
  const int lane = tid & 63, wave = tid >> 6;
  const int ln15 = lane & 15, quad = lane >> 4;

  // stage concatenated weight strip [col][k], hi/lo bf16 (zeros in pad rows)
  for (int e = tid; e < COLS*KALL; e += 256){
    const int k = e / COLS, c = e - k*COLS;
    const int gate = c / HHM, hh = c - gate*HHM;
    const int col = gate*H + m*HHM + hh;
    float w = 0.f;
    if (HAS_X){
      if (k < KX){ if (k < HprevReal) w = Wx[(size_t)k*N4H + col]; }
      else { const int k2 = k - KX; if (k2 < H) w = Wh[(size_t)k2*N4H + col]; }
    } else {
      if (k < H) w = Wh[(size_t)k*N4H + col];
    }
    const unsigned short hi = f2bf(w);
    whT_hi[c*KSTR + k] = hi;
    whT_lo[c*KSTR + k] = f2bf(w - bf2f(hi));
  }

  const int r_g  = tid / PR;
  const int hh0  = 2*(tid - r_g*PR);
  const int kidx = m*HHM + hh0;
  float c0 = 0.f, c1 = 0.f;
  if (tid < NE && t0 > 0){
    const float2 cv = *(const float2*)&cstate[(size_t)(row0 + r_g)*H + kidx];
    c0 = cv.x; c1 = cv.y;
  }
  float2 bv[4] = {};
  if (HAS_X){
    if (tid < NE){
      #pragma unroll
      for (int gate = 0; gate < 4; ++gate)
        bv[gate] = *(const float2*)&bias[gate*H + kidx];
    }
  }
  __syncthreads();

  // group counters (one line each)
  const unsigned* cOwn = ctrOwn + (size_t)g*FSTR;
  unsigned*       cOwnW = ctrOwn + (size_t)g*FSTR;
  const unsigned* cUp  = HAS_X  ? (ctrUp + (size_t)g*FSTR) : nullptr;
  const unsigned* cDn  = (PDn>0) ? (ctrDn + (size_t)g*FSTR) : nullptr;
  const bool isUpLane = (HAS_X && lane == 0);
  const bool isDnLane = (PDn > 0 && lane == 32);

  for (int tl = 0; tl < TC; ++tl){
    const int t = t0 + tl;

    // layer-0 pregate values (independent of h; overlaps the wait)
    float2 gv[4] = {};
    if constexpr (!HAS_X){
      if (tid < NE){
        const float* Gt = G0 + ((size_t)tl*128 + row0 + r_g)*(size_t)N4H + kidx;
        #pragma unroll
        for (int gate = 0; gate < 4; ++gate)
          gv[gate] = *(const float2*)(Gt + gate*H);
      }
    }

    // ---- phase 1: own-member wait (sum counter; one lane, one line) ----
    if (lane == 0)
      spin_ge(cOwn, (unsigned)(P * t));                 // all h_{t-1} published
    __builtin_amdgcn_fence(__ATOMIC_ACQUIRE, "wavefront");

    f32x4 acc[2];
    acc[0] = (f32x4){0.f,0.f,0.f,0.f};
    acc[1] = (f32x4){0.f,0.f,0.f,0.f};
    auto do_tile = [&](const short8& a_h, const short8& a_l, int koW){
      #pragma unroll
      for (int s = 0; s < 2; ++s){
        const int nt = wave + 4*s;
        if (nt < NT){
          const int boff = (nt*16 + ln15)*KSTR + quad*8 + koW;
          const short8 b_h = *(const short8*)&whT_hi[boff];
          const short8 b_l = *(const short8*)&whT_lo[boff];
          acc[s] = __builtin_amdgcn_mfma_f32_16x16x32_bf16(a_h, b_h, acc[s], 0,0,0);
          acc[s] = __builtin_amdgcn_mfma_f32_16x16x32_bf16(a_l, b_h, acc[s], 0,0,0);
          acc[s] = __builtin_amdgcn_mfma_f32_16x16x32_bf16(a_h, b_l, acc[s], 0,0,0);
        }
      }
    };

    // own-h part FIRST (per-tile load->MFMA, structure identical to R9)
    {
      const unsigned* own = HxOwn + ((size_t)((t-1) & 7)*8 + g) * SLOTo;
      #pragma unroll
      for (int kt = 0; kt < KTH; ++kt){
        short8 a_h, a_l;
        load_hx(own, ln15*RSo + kt*16 + quad*4, 16*RSo, a_h, a_l);
        do_tile(a_h, a_l, KX + kt*32);
      }
    }

    // ---- phase 2: upstream + backpressure wait (fused, disjoint lanes) ----
    {
      const bool act = (isUpLane) || (isDnLane && t >= 8);
      if (act){
        const unsigned* p2 = isUpLane ? cUp : cDn;
        const unsigned tgt = isUpLane ? (unsigned)(PUp * (t+1))
                                      : (unsigned)(PDn * (t-7));
        spin_ge(p2, tgt);
      }
    }
    __builtin_amdgcn_fence(__ATOMIC_ACQUIRE, "wavefront");

    // x-part MFMA (upstream h_t)
    if constexpr (HAS_X){
      const unsigned* up = HxUp + ((size_t)(t & 7)*8 + g) * SLOTp;
      #pragma unroll
      for (int kt = 0; kt < KTX; ++kt){
        short8 a_h, a_l;
        load_hx(up, ln15*RSp + kt*16 + quad*4, 16*RSp, a_h, a_l);
        do_tile(a_h, a_l, kt*32);
      }
    }

    {
      #pragma unroll
      for (int s = 0; s < 2; ++s){
        const int nt = wave + 4*s;
        if (nt < NT)
          #pragma unroll
          for (int r = 0; r < 4; ++r)
            zbuf[(quad*4 + r)*ZSTR + nt*16 + ln15] = acc[s][r];
      }
    }
    __syncthreads();   // B1: zbuf ready

    // gates + state update + publish h_t -> own slot t&7
    if (tid < NE){
      const float* zr = zbuf + r_g*ZSTR;
      const float2 b0 = HAS_X ? bv[0] : gv[0];
      const float2 b1 = HAS_X ? bv[1] : gv[1];
      const float2 b2 = HAS_X ? bv[2] : gv[2];
      const float2 b3 = HAS_X ? bv[3] : gv[3];
      const float zi0 = zr[0*HHM + hh0]   + b0.x, zi1 = zr[0*HHM + hh0+1] + b0.y;
      const float zf0 = zr[1*HHM + hh0]   + b1.x, zf1 = zr[1*HHM + hh0+1] + b1.y;
      const float zg0 = zr[2*HHM + hh0]   + b2.x, zg1 = zr[2*HHM + hh0+1] + b2.y;
      const float zo0 = zr[3*HHM + hh0]   + b3.x, zo1 = zr[3*HHM + hh0+1] + b3.y;
      c0 = sigmoidf_(zf0)*c0 + sigmoidf_(zi0)*tanhf_(zg0);
      c1 = sigmoidf_(zf1)*c1 + sigmoidf_(zi1)*tanhf_(zg1);
      const float h0 = sigmoidf_(zo0)*tanhf_(c0);
      const float h1 = sigmoidf_(zo1)*tanhf_(c1);
      const unsigned short h0h = f2bf(h0), h1h = f2bf(h1);
      const unsigned short h0l = f2bf(h0 - bf2f(h0h)), h1l = f2bf(h1 - bf2f(h1h));
      const unsigned whi = ((unsigned)h1h << 16) | (unsigned)h0h;
      const unsigned wlo = ((unsigned)h1l << 16) | (unsigned)h0l;
      unsigned* dst = HxOwn + ((size_t)(t & 7)*8 + g) * SLOTo;
      const int w32 = r_g*RSo + (kidx >> 1);
      __hip_atomic_store(&dst[w32],          whi, __ATOMIC_RELAXED, AGENT);
      __hip_atomic_store(&dst[16*RSo + w32], wlo, __ATOMIC_RELAXED, AGENT);
      if (hlast && t == Tlast-1){
        float2 hv{h0, h1};
        *(float2*)&hlast[(size_t)(row0 + r_g)*H + kidx] = hv;
      }
    }
    __syncthreads();   // B2: vmcnt(0)-drain per wave => h stores LLC-visible
    if (tid == 0)
      __hip_atomic_fetch_add(cOwnW, 1u, __ATOMIC_RELAXED, AGENT);
  }

  // persist c-state for the next chunk
  if (tid < NE){
    float2 cv{c0, c1};
    *(float2*)&cstate[(size_t)(row0 + r_g)*H + kidx] = cv;
  }
}

struct FusedArgs {
  const float *G0;
  const float *Wx1, *Wx2, *Wx3;
  const float *Wh0, *Wh1, *Wh2, *Wh3;
  const float *b1, *b2, *b3;
  unsigned *Hx0, *Hx1, *Hx2, *Hx3;
  unsigned *flags;                 // 4 layers x 8 groups x FSTR u32 (counters)
  float *cst;                      // 4 x 128 x 200
  float *hlast;
  int t0, TC, Tlast;
};

// Blocks: [0,40)=L0, [40,80)=L1, [80,160)=L2, [160,240)=L3.
__global__ __launch_bounds__(256) void lstm_fused(FusedArgs a){
  extern __shared__ char smem[];
  const int b = blockIdx.x;
  constexpr int LF = 8*FSTR;       // u32 per layer's counter region
  unsigned* F = a.flags;
  if (b < 40){
    rec_stage<100, 0, 5, false>(a.G0, nullptr, a.Wh0, nullptr, 0,
        nullptr, a.Hx0, nullptr, F + 0*LF, F + 1*LF, 0, 5,
        a.cst + 0*128*200, nullptr, b & 7, b >> 3, a.t0, a.TC, a.Tlast, smem);
  } else if (b < 80){
    const int bb = b - 40;
    rec_stage<100, 128, 5, true>(nullptr, a.Wx1, a.Wh1, a.b1, 100,
        a.Hx0, a.Hx1, F + 0*LF, F + 1*LF, F + 2*LF, 5, 10,
        a.cst + 1*128*200, nullptr, bb & 7, bb >> 3, a.t0, a.TC, a.Tlast, smem);
  } else if (b < 160){
    const int bb = b - 80;
    rec_stage<200, 128, 10, true>(nullptr, a.Wx2, a.Wh2, a.b2, 100,
        a.Hx1, a.Hx2, F + 1*LF, F + 2*LF, F + 3*LF, 5, 10,
        a.cst + 2*128*200, nullptr, bb & 7, bb >> 3, a.t0, a.TC, a.Tlast, smem);
  } else {
    const int bb = b - 160;
    rec_stage<200, 224, 10, true>(nullptr, a.Wx3, a.Wh3, a.b3, 200,
        a.Hx2, a.Hx3, F + 2*LF, F + 3*LF, nullptr, 10, 0,
        a.cst + 3*128*200, a.hlast, bb & 7, bb >> 3, a.t0, a.TC, a.Tlast, smem);
  }
}

// ---------------------------------------------------------------------------
__global__ __launch_bounds__(256) void head_kernel(
    const float* __restrict__ hlast, const float* __restrict__ Wd,
    const float* __restrict__ bd, float* __restrict__ out)
{
  const int e = blockIdx.x*256 + threadIdx.x;
  if (e >= 128*6) return;
  const int b = e / 6, o = e - 6*b;
  float s = bd[o];
  const float* hp = hlast + (size_t)b*200;
  for (int k = 0; k < 200; ++k) s += hp[k] * Wd[k*6 + o];
  out[e] = s;
}

__global__ void fill_sentinel(float* out, int n){
  const int i = blockIdx.x*blockDim.x + threadIdx.x;
  if (i < n) out[i] = 1.0e30f;
}

// ---------------------------------------------------------------------------
extern "C" void kernel_launch(void* const* d_in, const int* in_sizes, int n_in,
                              void* d_out, int out_size, void* d_ws, size_t ws_size,
                              hipStream_t stream)
{
  (void)in_sizes; (void)n_in;
  const float* xs  = (const float*)d_in[0];
  const float* Wx[4] = {(const float*)d_in[1], (const float*)d_in[4],
                        (const float*)d_in[7], (const float*)d_in[10]};
  const float* Wh[4] = {(const float*)d_in[2], (const float*)d_in[5],
                        (const float*)d_in[8], (const float*)d_in[11]};
  const float* bs[4] = {(const float*)d_in[3], (const float*)d_in[6],
                        (const float*)d_in[9], (const float*)d_in[12]};
  const float* Wd = (const float*)d_in[13];
  const float* bd = (const float*)d_in[14];
  float* out = (float*)d_out;

  // ---- workspace layout ----
  char* ws = (char*)d_ws;
  const size_t HXU[4] = {131072, 131072, 229376, 229376};   // u32 per layer
  const size_t HX_TOT = HXU[0]+HXU[1]+HXU[2]+HXU[3];
  const size_t FLAGS_BYTES = (size_t)4*8*FSTR*4;            // 8 KiB counters
  size_t off = 0;
  const size_t OFF_FLAGS = off; off += FLAGS_BYTES;
  const size_t OFF_HX    = off; off += HX_TOT*4;
  const size_t OFF_CST   = off; off += (size_t)4*128*200*4;
  const size_t OFF_HLAST = off; off += (size_t)128*200*4;
  off = (off + 255) & ~(size_t)255;
  const size_t FIXED_END = off;

  int CT = 0;
  for (int ct = 1024; ct >= 8; ct >>= 1){
    const size_t need = FIXED_END + (size_t)ct*128*400*4;   // G0 chunk only
    if (ws_size >= need){ CT = ct; break; }
  }
  if (CT == 0){
    fill_sentinel<<<(out_size + 255)/256, 256, 0, stream>>>(out, out_size);
    return;
  }

  unsigned* flags = (unsigned*)(ws + OFF_FLAGS);
  unsigned* Hx0   = (unsigned*)(ws + OFF_HX);
  unsigned* Hx1   = Hx0 + HXU[0];
  unsigned* Hx2   = Hx1 + HXU[1];
  unsigned* Hx3   = Hx2 + HXU[2];
  float* cst      = (float*)(ws + OFF_CST);
  float* hlast    = (float*)(ws + OFF_HLAST);
  float* G0       = (float*)(ws + FIXED_END);

  // L3 stage LDS: 2 planes * 80*456 shorts = 145920 B + zbuf 16*81*4 = 5184
  const int FUSED_LDS = 151104;
  hipFuncSetAttribute(reinterpret_cast<const void*>(lstm_fused),
                      hipFuncAttributeMaxDynamicSharedMemorySize, FUSED_LDS);

  hipMemsetAsync(flags, 0, FLAGS_BYTES, stream);
  hipMemsetAsync(Hx0, 0, HX_TOT*4, stream);

  FusedArgs fa;
  fa.Wx1 = Wx[1]; fa.Wx2 = Wx[2]; fa.Wx3 = Wx[3];
  fa.Wh0 = Wh[0]; fa.Wh1 = Wh[1]; fa.Wh2 = Wh[2]; fa.Wh3 = Wh[3];
  fa.b1 = bs[1];  fa.b2 = bs[2];  fa.b3 = bs[3];
  fa.Hx0 = Hx0; fa.Hx1 = Hx1; fa.Hx2 = Hx2; fa.Hx3 = Hx3;
  fa.flags = flags; fa.cst = cst; fa.hlast = hlast;
  fa.G0 = G0; fa.Tlast = 1024;

  const int NC  = 1024 / CT;
  const int GMX = CT*128/256;
  for (int c = 0; c < NC; ++c){
    const int t0 = c*CT;
    gemm_pregate<<<dim3(GMX,5), 256, 0, stream>>>(xs + (size_t)t0*128, Wx[0], bs[0], G0,
        128, 4, 400, (size_t)128, (size_t)131072);
    fa.t0 = t0; fa.TC = CT;
    lstm_fused<<<240, 256, FUSED_LDS, stream>>>(fa);
  }

  head_kernel<<<3, 256, 0, stream>>>(hlast, Wd, bd, out);
}

// Round 5
// 6652.474 us; speedup vs baseline: 1.1825x; 1.1825x over previous
//
#include <hip/hip_runtime.h>
#include <cstdint>
#include <cstddef>

// ============================================================================
// 4-layer LSTM (B=128, T=1024, D=128, H={100,100,200,200}) + linear head.
// R12 = R9 (best, 6474us) + batched a-fragment loads with the VGPR budget
// actually unlocked:
//  - __launch_bounds__(256,1): LDS (151KB) already forces 1 block/CU, so
//    VGPRs are free up to ~500; the default target capped R10's batch at
//    VGPR=100 -> spills/partial batching (its +1us regression).
//  - ALL x-part + own-part tile loads issued into raw u64 register arrays
//    (fully unrolled) BEFORE the MFMA phase: ~14 tile-loads in flight at
//    once => one aggregate LLC round trip instead of ~2-deep serialized
//    per-tile RTs (the invariant ~3-5us/step across R7-R11).
// Sync protocol, spins, barriers, zbuf, gates, publish: byte-identical R9.
// R11 lesson kept: no RMW fan-in (parallel per-member flag stores).
// ============================================================================

#define AGENT __HIP_MEMORY_SCOPE_AGENT
#define FSTR 64   // u32 stride between flags (256B sector per flag)

typedef __attribute__((ext_vector_type(8))) short  short8;
typedef __attribute__((ext_vector_type(4))) float  f32x4;

struct us4 { unsigned short x, y, z, w; };

__device__ __forceinline__ unsigned short f2bf(float x){
  unsigned u = __float_as_uint(x);
  unsigned r = u + 0x7FFFu + ((u >> 16) & 1u);   // RN-even to bf16
  return (unsigned short)(r >> 16);
}
__device__ __forceinline__ float bf2f(unsigned short h){
  return __uint_as_float(((unsigned)h) << 16);
}
__device__ __forceinline__ float sigmoidf_(float x){ return 1.f / (1.f + __expf(-x)); }
__device__ __forceinline__ float tanhf_(float x){
  // tanh(x) = 1 - 2/(1+e^{2x}); __expf saturates cleanly at both ends.
  return 1.f - 2.f / (1.f + __expf(2.f * x));
}

__device__ __forceinline__ void spin_ge(const unsigned* p, unsigned v){
  #pragma unroll 1
  for (int i = 0; i < 32; ++i){
    if (__hip_atomic_load(p, __ATOMIC_RELAXED, AGENT) >= v) return;
  }
  long s = 0;
  #pragma unroll 1
  while (__hip_atomic_load(p, __ATOMIC_RELAXED, AGENT) < v){
    __builtin_amdgcn_s_sleep(8);               // ~0.2us backoff
    if (++s > (1L << 17)) break;               // fail fast on true deadlock
  }
}

// ---------------------------------------------------------------------------
// K1: pregate GEMM for layer 0 only.  G[m][n] = xs_row(m) @ Wx0 + b0.
// ---------------------------------------------------------------------------
__global__ __launch_bounds__(256) void gemm_pregate(
    const float* __restrict__ A, const float* __restrict__ W,
    const float* __restrict__ bias, float* __restrict__ G,
    int K, int KT, int N, size_t strideT, size_t strideB)
{
  __shared__ unsigned short Ahi[256*40];
  __shared__ unsigned short Alo[256*40];
  __shared__ unsigned short Bhi[80*40];
  __shared__ unsigned short Blo[80*40];

  const int tid  = threadIdx.x;
  const int mb   = blockIdx.x;
  const int n0   = blockIdx.y * 80;
  const int wave = tid >> 6, lane = tid & 63;
  const int ln15 = lane & 15, quad = lane >> 4;

  f32x4 acc[4][5];
  for (int a = 0; a < 4; ++a)
    for (int b = 0; b < 5; ++b)
      acc[a][b] = (f32x4){0.f, 0.f, 0.f, 0.f};

  for (int kt = 0; kt < KT; ++kt){
    const int k0 = kt * 32;
    const bool full = (k0 + 31) < K;
    for (int i = 0; i < 8; ++i){
      const int e   = tid + 256*i;
      const int row = e >> 3, seg = e & 7;
      const int mm  = mb*256 + row;
      const float* rp = A + (size_t)(mm >> 7)*strideT + (size_t)(mm & 127)*strideB;
      const int k = k0 + seg*4;
      float v0, v1, v2, v3;
      if (full){
        float4 v = *(const float4*)(rp + k);
        v0 = v.x; v1 = v.y; v2 = v.z; v3 = v.w;
      } else {
        v0 = (k+0 < K) ? rp[k+0] : 0.f;
        v1 = (k+1 < K) ? rp[k+1] : 0.f;
        v2 = (k+2 < K) ? rp[k+2] : 0.f;
        v3 = (k+3 < K) ? rp[k+3] : 0.f;
      }
      const unsigned short h0=f2bf(v0), h1=f2bf(v1), h2=f2bf(v2), h3=f2bf(v3);
      us4 hv{h0, h1, h2, h3};
      us4 lv{f2bf(v0-bf2f(h0)), f2bf(v1-bf2f(h1)), f2bf(v2-bf2f(h2)), f2bf(v3-bf2f(h3))};
      *(us4*)&Ahi[row*40 + seg*4] = hv;
      *(us4*)&Alo[row*40 + seg*4] = lv;
    }
    for (int i = 0; i < 10; ++i){
      const int e  = tid + 256*i;
      const int kk = e / 80, nn = e - kk*80;
      const int k  = k0 + kk;
      const float v = (k < K) ? W[(size_t)k*N + n0 + nn] : 0.f;
      const unsigned short hb = f2bf(v);
      Bhi[nn*40 + kk] = hb;
      Blo[nn*40 + kk] = f2bf(v - bf2f(hb));
    }
    __syncthreads();
    short8 a_h[4], a_l[4];
    for (int mt = 0; mt < 4; ++mt){
      const int aoff = (wave*64 + mt*16 + ln15)*40 + quad*8;
      a_h[mt] = *(const short8*)&Ahi[aoff];
      a_l[mt] = *(const short8*)&Alo[aoff];
    }
    for (int nt = 0; nt < 5; ++nt){
      const int boff = (nt*16 + ln15)*40 + quad*8;
      const short8 b_h = *(const short8*)&Bhi[boff];
      const short8 b_l = *(const short8*)&Blo[boff];
      for (int mt = 0; mt < 4; ++mt){
        acc[mt][nt] = __builtin_amdgcn_mfma_f32_16x16x32_bf16(a_h[mt], b_h, acc[mt][nt], 0,0,0);
        acc[mt][nt] = __builtin_amdgcn_mfma_f32_16x16x32_bf16(a_l[mt], b_h, acc[mt][nt], 0,0,0);
        acc[mt][nt] = __builtin_amdgcn_mfma_f32_16x16x32_bf16(a_h[mt], b_l, acc[mt][nt], 0,0,0);
      }
    }
    __syncthreads();
  }
  for (int nt = 0; nt < 5; ++nt){
    const float bv = bias[n0 + nt*16 + ln15];
    for (int mt = 0; mt < 4; ++mt){
      const int mbase = mb*256 + wave*64 + mt*16 + quad*4;
      #pragma unroll
      for (int r = 0; r < 4; ++r)
        G[(size_t)(mbase + r)*N + n0 + nt*16 + ln15] = acc[mt][nt][r] + bv;
    }
  }
}

// ---------------------------------------------------------------------------
// Fused pipeline stage (window-8 h slots, per-wave two-phase waits,
// fully-batched a-fragment loads).
// Hx layout per layer: [slot(8)][group(8)][plane hi/lo][16 rows][RS u32].
// Flags: index (g*16 + member) * FSTR.
// ---------------------------------------------------------------------------
template<int H, int HP, int P, bool HAS_X>
__device__ __forceinline__ void rec_stage(
    const float* __restrict__ G0, const float* __restrict__ Wx,
    const float* __restrict__ Wh, const float* __restrict__ bias,
    int HprevReal,
    const unsigned* __restrict__ HxUp, unsigned* __restrict__ HxOwn,
    const unsigned* __restrict__ flgUp, unsigned* __restrict__ flgOwn,
    unsigned* __restrict__ flgDn, int PUp, int PDn,
    float* __restrict__ cstate, float* __restrict__ hlast,
    int g, int m, int t0, int TC, int Tlast, char* smem)
{
  constexpr int HHM  = H / P;                 // 20
  constexpr int COLS = 4 * HHM;               // 80
  constexpr int CP   = COLS;
  constexpr int ZSTR = CP + 1;                // zbuf row stride (pad)
  constexpr int KPo  = ((H + 31)/32)*32;      // own-h padded K
  constexpr int RSo  = KPo / 2;               // own Hx row stride (u32)
  constexpr int RSp  = HP / 2;                // upstream Hx row stride
  constexpr int KX   = HAS_X ? HP : 0;
  constexpr int KALL = KX + KPo;
  constexpr int KTX  = KX / 32;
  constexpr int KTH  = KPo / 32;
  constexpr int KSTR = KALL + 8;
  constexpr int NT   = CP / 16;               // 5
  constexpr int NE   = 16 * HHM / 2;          // 160
  constexpr int PR   = HHM / 2;               // 10
  constexpr int N4H  = 4 * H;
  constexpr int SLOTo = 2*16*RSo;             // u32 per (slot,group), own
  constexpr int SLOTp = 2*16*RSp;             // u32 per (slot,group), upstream
  constexpr int KTXA = HAS_X ? KTX : 1;       // array-size helper

  unsigned short* whT_hi = (unsigned short*)smem;
  unsigned short* whT_lo = whT_hi + CP*KSTR;
  float* zbuf = (float*)(whT_lo + CP*KSTR);   // [16][ZSTR]

  const int tid  = threadIdx.x;
  const int row0 = g * 16;
  const int lane = tid & 63, wave = tid >> 6;
  const int ln15 = lane & 15, quad = lane >> 4;

  // stage concatenated weight strip [col][k], hi/lo bf16 (zeros in pad rows)
  for (int e = tid; e < COLS*KALL; e += 256){
    const int k = e / COLS, c = e - k*COLS;
    const int gate = c / HHM, hh = c - gate*HHM;
    const int col = gate*H + m*HHM + hh;
    float w = 0.f;
    if (HAS_X){
      if (k < KX){ if (k < HprevReal) w = Wx[(size_t)k*N4H + col]; }
      else { const int k2 = k - KX; if (k2 < H) w = Wh[(size_t)k2*N4H + col]; }
    } else {
      if (k < H) w = Wh[(size_t)k*N4H + col];
    }
    const unsigned short hi = f2bf(w);
    whT_hi[c*KSTR + k] = hi;
    whT_lo[c*KSTR + k] = f2bf(w - bf2f(hi));
  }

  const int r_g  = tid / PR;
  const int hh0  = 2*(tid - r_g*PR);
  const int kidx = m*HHM + hh0;
  float c0 = 0.f, c1 = 0.f;
  if (tid < NE && t0 > 0){
    const float2 cv = *(const float2*)&cstate[(size_t)(row0 + r_g)*H + kidx];
    c0 = cv.x; c1 = cv.y;
  }
  float2 bv[4] = {};
  if (HAS_X){
    if (tid < NE){
      #pragma unroll
      for (int gate = 0; gate < 4; ++gate)
        bv[gate] = *(const float2*)&bias[gate*H + kidx];
    }
  }
  __syncthreads();

  const int g16 = g*16;

  for (int tl = 0; tl < TC; ++tl){
    const int t = t0 + tl;

    // layer-0 pregate values (independent of h; overlaps the waits)
    float2 gv[4] = {};
    if constexpr (!HAS_X){
      if (tid < NE){
        const float* Gt = G0 + ((size_t)tl*128 + row0 + r_g)*(size_t)N4H + kidx;
        #pragma unroll
        for (int gate = 0; gate < 4; ++gate)
          gv[gate] = *(const float2*)(Gt + gate*H);
      }
    }

    // ---- phase A: per-wave upstream wait (no barrier) ----
    if (HAS_X && lane < PUp)
      spin_ge(&flgUp[(size_t)(g16 + lane)*FSTR], (unsigned)(t+1));  // h^up_t
    __builtin_amdgcn_fence(__ATOMIC_ACQUIRE, "wavefront");          // compiler order

    // ---- issue ALL x-part a-fragment loads (independent, stay in flight) ----
    unsigned long long xq[KTXA][4];
    if constexpr (HAS_X){
      const unsigned* up = HxUp + ((size_t)(t & 7)*8 + g) * SLOTp;
      #pragma unroll
      for (int kt = 0; kt < KTX; ++kt){
        const int w32 = ln15*RSp + kt*16 + quad*4;
        const unsigned long long* ph = (const unsigned long long*)(up + w32);
        const unsigned long long* pl = (const unsigned long long*)(up + 16*RSp + w32);
        xq[kt][0] = __hip_atomic_load(ph + 0, __ATOMIC_RELAXED, AGENT);
        xq[kt][1] = __hip_atomic_load(ph + 1, __ATOMIC_RELAXED, AGENT);
        xq[kt][2] = __hip_atomic_load(pl + 0, __ATOMIC_RELAXED, AGENT);
        xq[kt][3] = __hip_atomic_load(pl + 1, __ATOMIC_RELAXED, AGENT);
      }
    }

    // ---- phase B: per-wave own-member wait (skip self) + backpressure ----
    if (lane < P && lane != m)
      spin_ge(&flgOwn[(size_t)(g16 + lane)*FSTR], (unsigned)t);     // h_{t-1}
    if (PDn > 0 && t >= 8 && lane >= 40 && lane < 40 + PDn)
      spin_ge(&flgDn[(size_t)(g16 + (lane-40))*FSTR], (unsigned)(t-7)); // slot free
    __builtin_amdgcn_fence(__ATOMIC_ACQUIRE, "wavefront");          // compiler order

    // ---- issue ALL own-part loads ----
    unsigned long long oq[KTH][4];
    {
      const unsigned* own = HxOwn + ((size_t)((t-1) & 7)*8 + g) * SLOTo;
      #pragma unroll
      for (int kt = 0; kt < KTH; ++kt){
        const int w32 = ln15*RSo + kt*16 + quad*4;
        const unsigned long long* ph = (const unsigned long long*)(own + w32);
        const unsigned long long* pl = (const unsigned long long*)(own + 16*RSo + w32);
        oq[kt][0] = __hip_atomic_load(ph + 0, __ATOMIC_RELAXED, AGENT);
        oq[kt][1] = __hip_atomic_load(ph + 1, __ATOMIC_RELAXED, AGENT);
        oq[kt][2] = __hip_atomic_load(pl + 0, __ATOMIC_RELAXED, AGENT);
        oq[kt][3] = __hip_atomic_load(pl + 1, __ATOMIC_RELAXED, AGENT);
      }
    }

    // ---- MFMA over all tiles (per-tile waitcnts are counted, not 0) ----
    f32x4 acc[2];
    acc[0] = (f32x4){0.f,0.f,0.f,0.f};
    acc[1] = (f32x4){0.f,0.f,0.f,0.f};
    auto do_tile = [&](const short8& a_h, const short8& a_l, int koW){
      #pragma unroll
      for (int s = 0; s < 2; ++s){
        const int nt = wave + 4*s;
        if (nt < NT){
          const int boff = (nt*16 + ln15)*KSTR + quad*8 + koW;
          const short8 b_h = *(const short8*)&whT_hi[boff];
          const short8 b_l = *(const short8*)&whT_lo[boff];
          acc[s] = __builtin_amdgcn_mfma_f32_16x16x32_bf16(a_h, b_h, acc[s], 0,0,0);
          acc[s] = __builtin_amdgcn_mfma_f32_16x16x32_bf16(a_l, b_h, acc[s], 0,0,0);
          acc[s] = __builtin_amdgcn_mfma_f32_16x16x32_bf16(a_h, b_l, acc[s], 0,0,0);
        }
      }
    };

    union U2 { unsigned long long q[2]; short8 v; };
    if constexpr (HAS_X){
      #pragma unroll
      for (int kt = 0; kt < KTX; ++kt){
        U2 ua, ub;
        ua.q[0] = xq[kt][0]; ua.q[1] = xq[kt][1];
        ub.q[0] = xq[kt][2]; ub.q[1] = xq[kt][3];
        do_tile(ua.v, ub.v, kt*32);
      }
    }
    {
      #pragma unroll
      for (int kt = 0; kt < KTH; ++kt){
        U2 ua, ub;
        ua.q[0] = oq[kt][0]; ua.q[1] = oq[kt][1];
        ub.q[0] = oq[kt][2]; ub.q[1] = oq[kt][3];
        do_tile(ua.v, ub.v, KX + kt*32);
      }
    }

    {
      #pragma unroll
      for (int s = 0; s < 2; ++s){
        const int nt = wave + 4*s;
        if (nt < NT)
          #pragma unroll
          for (int r = 0; r < 4; ++r)
            zbuf[(quad*4 + r)*ZSTR + nt*16 + ln15] = acc[s][r];
      }
    }
    __syncthreads();   // B1: zbuf ready

    // gates + state update + publish h_t -> own slot t&7
    if (tid < NE){
      const float* zr = zbuf + r_g*ZSTR;
      const float2 b0 = HAS_X ? bv[0] : gv[0];
      const float2 b1 = HAS_X ? bv[1] : gv[1];
      const float2 b2 = HAS_X ? bv[2] : gv[2];
      const float2 b3 = HAS_X ? bv[3] : gv[3];
      const float zi0 = zr[0*HHM + hh0]   + b0.x, zi1 = zr[0*HHM + hh0+1] + b0.y;
      const float zf0 = zr[1*HHM + hh0]   + b1.x, zf1 = zr[1*HHM + hh0+1] + b1.y;
      const float zg0 = zr[2*HHM + hh0]   + b2.x, zg1 = zr[2*HHM + hh0+1] + b2.y;
      const float zo0 = zr[3*HHM + hh0]   + b3.x, zo1 = zr[3*HHM + hh0+1] + b3.y;
      c0 = sigmoidf_(zf0)*c0 + sigmoidf_(zi0)*tanhf_(zg0);
      c1 = sigmoidf_(zf1)*c1 + sigmoidf_(zi1)*tanhf_(zg1);
      const float h0 = sigmoidf_(zo0)*tanhf_(c0);
      const float h1 = sigmoidf_(zo1)*tanhf_(c1);
      const unsigned short h0h = f2bf(h0), h1h = f2bf(h1);
      const unsigned short h0l = f2bf(h0 - bf2f(h0h)), h1l = f2bf(h1 - bf2f(h1h));
      const unsigned whi = ((unsigned)h1h << 16) | (unsigned)h0h;
      const unsigned wlo = ((unsigned)h1l << 16) | (unsigned)h0l;
      unsigned* dst = HxOwn + ((size_t)(t & 7)*8 + g) * SLOTo;
      const int w32 = r_g*RSo + (kidx >> 1);
      __hip_atomic_store(&dst[w32],          whi, __ATOMIC_RELAXED, AGENT);
      __hip_atomic_store(&dst[16*RSo + w32], wlo, __ATOMIC_RELAXED, AGENT);
      if (hlast && t == Tlast-1){
        float2 hv{h0, h1};
        *(float2*)&hlast[(size_t)(row0 + r_g)*H + kidx] = hv;
      }
    }
    __syncthreads();   // B2: vmcnt(0)-drain per wave => h stores LLC-visible
    if (tid == 0)
      __hip_atomic_store(&flgOwn[(size_t)(g16 + m)*FSTR], (unsigned)(t+1),
                         __ATOMIC_RELAXED, AGENT);
  }

  // persist c-state for the next chunk
  if (tid < NE){
    float2 cv{c0, c1};
    *(float2*)&cstate[(size_t)(row0 + r_g)*H + kidx] = cv;
  }
}

struct FusedArgs {
  const float *G0;
  const float *Wx1, *Wx2, *Wx3;
  const float *Wh0, *Wh1, *Wh2, *Wh3;
  const float *b1, *b2, *b3;
  unsigned *Hx0, *Hx1, *Hx2, *Hx3;
  unsigned *flags;                 // 4 layers x 128 flags x FSTR u32
  float *cst;                      // 4 x 128 x 200
  float *hlast;
  int t0, TC, Tlast;
};

// Blocks: [0,40)=L0, [40,80)=L1, [80,160)=L2, [160,240)=L3.
// (256,1): LDS already limits to 1 block/CU; free the VGPR budget so the
// batched tile loads stay in registers (R10 spilled at the default cap).
__global__ __launch_bounds__(256, 1) void lstm_fused(FusedArgs a){
  extern __shared__ char smem[];
  const int b = blockIdx.x;
  constexpr int LF = 128*FSTR;     // u32 per layer's flag region
  if (b < 40){
    rec_stage<100, 0, 5, false>(a.G0, nullptr, a.Wh0, nullptr, 0,
        nullptr, a.Hx0, nullptr, a.flags + 0*LF, a.flags + 1*LF, 0, 5,
        a.cst + 0*128*200, nullptr, b & 7, b >> 3, a.t0, a.TC, a.Tlast, smem);
  } else if (b < 80){
    const int bb = b - 40;
    rec_stage<100, 128, 5, true>(nullptr, a.Wx1, a.Wh1, a.b1, 100,
        a.Hx0, a.Hx1, a.flags + 0*LF, a.flags + 1*LF, a.flags + 2*LF, 5, 10,
        a.cst + 1*128*200, nullptr, bb & 7, bb >> 3, a.t0, a.TC, a.Tlast, smem);
  } else if (b < 160){
    const int bb = b - 80;
    rec_stage<200, 128, 10, true>(nullptr, a.Wx2, a.Wh2, a.b2, 100,
        a.Hx1, a.Hx2, a.flags + 1*LF, a.flags + 2*LF, a.flags + 3*LF, 5, 10,
        a.cst + 2*128*200, nullptr, bb & 7, bb >> 3, a.t0, a.TC, a.Tlast, smem);
  } else {
    const int bb = b - 160;
    rec_stage<200, 224, 10, true>(nullptr, a.Wx3, a.Wh3, a.b3, 200,
        a.Hx2, a.Hx3, a.flags + 2*LF, a.flags + 3*LF, nullptr, 10, 0,
        a.cst + 3*128*200, a.hlast, bb & 7, bb >> 3, a.t0, a.TC, a.Tlast, smem);
  }
}

// ---------------------------------------------------------------------------
__global__ __launch_bounds__(256) void head_kernel(
    const float* __restrict__ hlast, const float* __restrict__ Wd,
    const float* __restrict__ bd, float* __restrict__ out)
{
  const int e = blockIdx.x*256 + threadIdx.x;
  if (e >= 128*6) return;
  const int b = e / 6, o = e - 6*b;
  float s = bd[o];
  const float* hp = hlast + (size_t)b*200;
  for (int k = 0; k < 200; ++k) s += hp[k] * Wd[k*6 + o];
  out[e] = s;
}

__global__ void fill_sentinel(float* out, int n){
  const int i = blockIdx.x*blockDim.x + threadIdx.x;
  if (i < n) out[i] = 1.0e30f;
}

// ---------------------------------------------------------------------------
extern "C" void kernel_launch(void* const* d_in, const int* in_sizes, int n_in,
                              void* d_out, int out_size, void* d_ws, size_t ws_size,
                              hipStream_t stream)
{
  (void)in_sizes; (void)n_in;
  const float* xs  = (const float*)d_in[0];
  const float* Wx[4] = {(const float*)d_in[1], (const float*)d_in[4],
                        (const float*)d_in[7], (const float*)d_in[10]};
  const float* Wh[4] = {(const float*)d_in[2], (const float*)d_in[5],
                        (const float*)d_in[8], (const float*)d_in[11]};
  const float* bs[4] = {(const float*)d_in[3], (const float*)d_in[6],
                        (const float*)d_in[9], (const float*)d_in[12]};
  const float* Wd = (const float*)d_in[13];
  const float* bd = (const float*)d_in[14];
  float* out = (float*)d_out;

  // ---- workspace layout ----
  char* ws = (char*)d_ws;
  const size_t HXU[4] = {131072, 131072, 229376, 229376};   // u32 per layer
  const size_t HX_TOT = HXU[0]+HXU[1]+HXU[2]+HXU[3];
  const size_t FLAGS_BYTES = (size_t)4*128*FSTR*4;          // 128 KiB
  size_t off = 0;
  const size_t OFF_FLAGS = off; off += FLAGS_BYTES;
  const size_t OFF_HX    = off; off += HX_TOT*4;
  const size_t OFF_CST   = off; off += (size_t)4*128*200*4;
  const size_t OFF_HLAST = off; off += (size_t)128*200*4;
  off = (off + 255) & ~(size_t)255;
  const size_t FIXED_END = off;

  int CT = 0;
  for (int ct = 1024; ct >= 8; ct >>= 1){
    const size_t need = FIXED_END + (size_t)ct*128*400*4;   // G0 chunk only
    if (ws_size >= need){ CT = ct; break; }
  }
  if (CT == 0){
    fill_sentinel<<<(out_size + 255)/256, 256, 0, stream>>>(out, out_size);
    return;
  }

  unsigned* flags = (unsigned*)(ws + OFF_FLAGS);
  unsigned* Hx0   = (unsigned*)(ws + OFF_HX);
  unsigned* Hx1   = Hx0 + HXU[0];
  unsigned* Hx2   = Hx1 + HXU[1];
  unsigned* Hx3   = Hx2 + HXU[2];
  float* cst      = (float*)(ws + OFF_CST);
  float* hlast    = (float*)(ws + OFF_HLAST);
  float* G0       = (float*)(ws + FIXED_END);

  // L3 stage LDS: 2 planes * 80*456 shorts = 145920 B + zbuf 16*81*4 = 5184
  const int FUSED_LDS = 151104;
  hipFuncSetAttribute(reinterpret_cast<const void*>(lstm_fused),
                      hipFuncAttributeMaxDynamicSharedMemorySize, FUSED_LDS);

  hipMemsetAsync(flags, 0, FLAGS_BYTES, stream);
  hipMemsetAsync(Hx0, 0, HX_TOT*4, stream);

  FusedArgs fa;
  fa.Wx1 = Wx[1]; fa.Wx2 = Wx[2]; fa.Wx3 = Wx[3];
  fa.Wh0 = Wh[0]; fa.Wh1 = Wh[1]; fa.Wh2 = Wh[2]; fa.Wh3 = Wh[3];
  fa.b1 = bs[1];  fa.b2 = bs[2];  fa.b3 = bs[3];
  fa.Hx0 = Hx0; fa.Hx1 = Hx1; fa.Hx2 = Hx2; fa.Hx3 = Hx3;
  fa.flags = flags; fa.cst = cst; fa.hlast = hlast;
  fa.G0 = G0; fa.Tlast = 1024;

  const int NC  = 1024 / CT;
  const int GMX = CT*128/256;
  for (int c = 0; c < NC; ++c){
    const int t0 = c*CT;
    gemm_pregate<<<dim3(GMX,5), 256, 0, stream>>>(xs + (size_t)t0*128, Wx[0], bs[0], G0,
        128, 4, 400, (size_t)128, (size_t)131072);
    fa.t0 = t0; fa.TC = CT;
    lstm_fused<<<240, 256, FUSED_LDS, stream>>>(fa);
  }

  head_kernel<<<3, 256, 0, stream>>>(hlast, Wd, bd, out);
}

// Round 6
// 6085.782 us; speedup vs baseline: 1.2926x; 1.0931x over previous
//
#include <hip/hip_runtime.h>
#include <cstdint>
#include <cstddef>

// ============================================================================
// 4-layer LSTM (B=128, T=1024, D=128, H={100,100,200,200}) + linear head.
// R13 = R9 (best, 6474us) + HBM-traffic elimination:
//  - G0 pregate stream DELETED (was 210MB write + 210MB read = 49% of all
//    HBM bytes; dur tracked hbm_bytes/~133GB/s in every round R7-R12).
//    L0 now computes its x-part in-block like L1-3: weight strip is
//    [Wx0;Wh0], x a-fragments built by reading xs directly (plain cached
//    loads, L2-resident) + f32->bf16 hi/lo in-register conversion.
//  - gemm_pregate kernel, G0 workspace, and chunking loop all removed:
//    ONE lstm_fused launch for all 1024 steps.
// Sync protocol/windows/layout byte-identical to R9: window-8 h slots,
// per-wave two-phase spins, per-tile load->MFMA (R12 batching reverted),
// parallel per-member flags (R11 lesson), fast tanh (R10, absmax-neutral).
// ============================================================================

#define AGENT __HIP_MEMORY_SCOPE_AGENT
#define FSTR 64   // u32 stride between flags (256B sector per flag)

typedef __attribute__((ext_vector_type(8))) short  short8;
typedef __attribute__((ext_vector_type(4))) float  f32x4;

__device__ __forceinline__ unsigned short f2bf(float x){
  unsigned u = __float_as_uint(x);
  unsigned r = u + 0x7FFFu + ((u >> 16) & 1u);   // RN-even to bf16
  return (unsigned short)(r >> 16);
}
__device__ __forceinline__ float bf2f(unsigned short h){
  return __uint_as_float(((unsigned)h) << 16);
}
__device__ __forceinline__ float sigmoidf_(float x){ return 1.f / (1.f + __expf(-x)); }
__device__ __forceinline__ float tanhf_(float x){
  // tanh(x) = 1 - 2/(1+e^{2x}); __expf saturates cleanly at both ends.
  return 1.f - 2.f / (1.f + __expf(2.f * x));
}

__device__ __forceinline__ void spin_ge(const unsigned* p, unsigned v){
  #pragma unroll 1
  for (int i = 0; i < 32; ++i){
    if (__hip_atomic_load(p, __ATOMIC_RELAXED, AGENT) >= v) return;
  }
  long s = 0;
  #pragma unroll 1
  while (__hip_atomic_load(p, __ATOMIC_RELAXED, AGENT) < v){
    __builtin_amdgcn_s_sleep(8);               // ~0.2us backoff
    if (++s > (1L << 17)) break;               // fail fast on true deadlock
  }
}

__device__ __forceinline__ void load_hx(const unsigned* base, int w32, int loOff,
                                        short8& ah, short8& al){
  union U { unsigned long long q[2]; short8 v; } uh, ul;
  const unsigned long long* ph = (const unsigned long long*)(base + w32);
  const unsigned long long* pl = (const unsigned long long*)(base + loOff + w32);
  uh.q[0] = __hip_atomic_load(ph + 0, __ATOMIC_RELAXED, AGENT);
  uh.q[1] = __hip_atomic_load(ph + 1, __ATOMIC_RELAXED, AGENT);
  ul.q[0] = __hip_atomic_load(pl + 0, __ATOMIC_RELAXED, AGENT);
  ul.q[1] = __hip_atomic_load(pl + 1, __ATOMIC_RELAXED, AGENT);
  ah = uh.v; al = ul.v;
}

// ---------------------------------------------------------------------------
// Fused pipeline stage (window-8 h slots, per-wave two-phase waits).
// XS_IN=true (layer 0): x-part a-fragments come from xs (plain f32 loads +
// in-register bf16 hi/lo conversion); no upstream flag wait.
// XS_IN=false (layers 1-3): x-part from upstream Hx slots (agent atomics).
// Hx layout per layer: [slot(8)][group(8)][plane hi/lo][16 rows][RS u32].
// Flags: index (g*16 + member) * FSTR.
// ---------------------------------------------------------------------------
template<int H, int HP, int P, bool XS_IN>
__device__ __forceinline__ void rec_stage(
    const float* __restrict__ xs,
    const float* __restrict__ Wx, const float* __restrict__ Wh,
    const float* __restrict__ bias, int HprevReal,
    const unsigned* __restrict__ HxUp, unsigned* __restrict__ HxOwn,
    const unsigned* __restrict__ flgUp, unsigned* __restrict__ flgOwn,
    unsigned* __restrict__ flgDn, int PUp, int PDn,
    float* __restrict__ cstate, float* __restrict__ hlast,
    int g, int m, int t0, int TC, int Tlast, char* smem)
{
  constexpr int HHM  = H / P;                 // 20
  constexpr int COLS = 4 * HHM;               // 80
  constexpr int ZSTR = COLS + 1;              // zbuf row stride (pad)
  constexpr int KPo  = ((H + 31)/32)*32;      // own-h padded K
  constexpr int RSo  = KPo / 2;               // own Hx row stride (u32)
  constexpr int RSp  = HP / 2;                // upstream Hx row stride
  constexpr int KX   = HP;                    // x-part K (xs D or upstream Hp)
  constexpr int KALL = KX + KPo;
  constexpr int KTX  = KX / 32;
  constexpr int KTH  = KPo / 32;
  constexpr int KSTR = KALL + 8;
  constexpr int NT   = COLS / 16;             // 5
  constexpr int NE   = 16 * HHM / 2;          // 160
  constexpr int PR   = HHM / 2;               // 10
  constexpr int N4H  = 4 * H;
  constexpr int SLOTo = 2*16*RSo;             // u32 per (slot,group), own
  constexpr int SLOTp = 2*16*RSp;             // u32 per (slot,group), upstream

  unsigned short* whT_hi = (unsigned short*)smem;
  unsigned short* whT_lo = whT_hi + COLS*KSTR;
  float* zbuf = (float*)(whT_lo + COLS*KSTR);   // [16][ZSTR]

  const int tid  = threadIdx.x;
  const int row0 = g * 16;
  const int lane = tid & 63, wave = tid >> 6;
  const int ln15 = lane & 15, quad = lane >> 4;

  // stage concatenated weight strip [col][k] = [Wx; Wh], hi/lo bf16
  for (int e = tid; e < COLS*KALL; e += 256){
    const int k = e / COLS, c = e - k*COLS;
    const int gate = c / HHM, hh = c - gate*HHM;
    const int col = gate*H + m*HHM + hh;
    float w = 0.f;
    if (k < KX){ if (k < HprevReal) w = Wx[(size_t)k*N4H + col]; }
    else { const int k2 = k - KX; if (k2 < H) w = Wh[(size_t)k2*N4H + col]; }
    const unsigned short hi = f2bf(w);
    whT_hi[c*KSTR + k] = hi;
    whT_lo[c*KSTR + k] = f2bf(w - bf2f(hi));
  }

  const int r_g  = tid / PR;
  const int hh0  = 2*(tid - r_g*PR);
  const int kidx = m*HHM + hh0;
  float c0 = 0.f, c1 = 0.f;
  if (tid < NE && t0 > 0){
    const float2 cv = *(const float2*)&cstate[(size_t)(row0 + r_g)*H + kidx];
    c0 = cv.x; c1 = cv.y;
  }
  float2 bv[4] = {};
  if (tid < NE){
    #pragma unroll
    for (int gate = 0; gate < 4; ++gate)
      bv[gate] = *(const float2*)&bias[gate*H + kidx];
  }
  __syncthreads();

  const int g16 = g*16;

  for (int tl = 0; tl < TC; ++tl){
    const int t = t0 + tl;

    // ---- phase A: per-wave upstream wait (layers 1-3 only) ----
    if constexpr (!XS_IN){
      if (lane < PUp)
        spin_ge(&flgUp[(size_t)(g16 + lane)*FSTR], (unsigned)(t+1));  // h^up_t
      __builtin_amdgcn_fence(__ATOMIC_ACQUIRE, "wavefront");          // compiler order
    }

    f32x4 acc[2];
    acc[0] = (f32x4){0.f,0.f,0.f,0.f};
    acc[1] = (f32x4){0.f,0.f,0.f,0.f};
    auto do_tile = [&](const short8& a_h, const short8& a_l, int koW){
      #pragma unroll
      for (int s = 0; s < 2; ++s){
        const int nt = wave + 4*s;
        if (nt < NT){
          const int boff = (nt*16 + ln15)*KSTR + quad*8 + koW;
          const short8 b_h = *(const short8*)&whT_hi[boff];
          const short8 b_l = *(const short8*)&whT_lo[boff];
          acc[s] = __builtin_amdgcn_mfma_f32_16x16x32_bf16(a_h, b_h, acc[s], 0,0,0);
          acc[s] = __builtin_amdgcn_mfma_f32_16x16x32_bf16(a_l, b_h, acc[s], 0,0,0);
          acc[s] = __builtin_amdgcn_mfma_f32_16x16x32_bf16(a_h, b_l, acc[s], 0,0,0);
        }
      }
    };

    // x-part MFMA: xs-direct (L0) or upstream slot (L1-3)
    if constexpr (XS_IN){
      // xs[b][t][d]: row = row0+ln15, d = kt*32 + quad*8 + j
      const float* xp = xs + (size_t)(row0 + ln15)*(1024*128)
                           + (size_t)t*128 + quad*8;
      #pragma unroll
      for (int kt = 0; kt < KTX; ++kt){
        const float4 v0 = *(const float4*)(xp + kt*32);
        const float4 v1 = *(const float4*)(xp + kt*32 + 4);
        const float xv[8] = {v0.x, v0.y, v0.z, v0.w, v1.x, v1.y, v1.z, v1.w};
        union SU { unsigned short u[8]; short8 v; } sh, sl;
        #pragma unroll
        for (int j = 0; j < 8; ++j){
          const unsigned short hi = f2bf(xv[j]);
          sh.u[j] = hi;
          sl.u[j] = f2bf(xv[j] - bf2f(hi));
        }
        do_tile(sh.v, sl.v, kt*32);
      }
    } else {
      const unsigned* up = HxUp + ((size_t)(t & 7)*8 + g) * SLOTp;
      #pragma unroll
      for (int kt = 0; kt < KTX; ++kt){
        short8 a_h, a_l;
        load_hx(up, ln15*RSp + kt*16 + quad*4, 16*RSp, a_h, a_l);
        do_tile(a_h, a_l, kt*32);
      }
    }

    // ---- phase B: per-wave own-member wait (skip self) + backpressure ----
    if (lane < P && lane != m)
      spin_ge(&flgOwn[(size_t)(g16 + lane)*FSTR], (unsigned)t);     // h_{t-1}
    if (PDn > 0 && t >= 8 && lane >= 40 && lane < 40 + PDn)
      spin_ge(&flgDn[(size_t)(g16 + (lane-40))*FSTR], (unsigned)(t-7)); // slot free
    __builtin_amdgcn_fence(__ATOMIC_ACQUIRE, "wavefront");          // compiler order

    {
      const unsigned* own = HxOwn + ((size_t)((t-1) & 7)*8 + g) * SLOTo;
      #pragma unroll
      for (int kt = 0; kt < KTH; ++kt){
        short8 a_h, a_l;
        load_hx(own, ln15*RSo + kt*16 + quad*4, 16*RSo, a_h, a_l);
        do_tile(a_h, a_l, KX + kt*32);
      }
    }
    {
      #pragma unroll
      for (int s = 0; s < 2; ++s){
        const int nt = wave + 4*s;
        if (nt < NT)
          #pragma unroll
          for (int r = 0; r < 4; ++r)
            zbuf[(quad*4 + r)*ZSTR + nt*16 + ln15] = acc[s][r];
      }
    }
    __syncthreads();   // B1: zbuf ready

    // gates + state update + publish h_t -> own slot t&7
    if (tid < NE){
      const float* zr = zbuf + r_g*ZSTR;
      const float zi0 = zr[0*HHM + hh0]   + bv[0].x, zi1 = zr[0*HHM + hh0+1] + bv[0].y;
      const float zf0 = zr[1*HHM + hh0]   + bv[1].x, zf1 = zr[1*HHM + hh0+1] + bv[1].y;
      const float zg0 = zr[2*HHM + hh0]   + bv[2].x, zg1 = zr[2*HHM + hh0+1] + bv[2].y;
      const float zo0 = zr[3*HHM + hh0]   + bv[3].x, zo1 = zr[3*HHM + hh0+1] + bv[3].y;
      c0 = sigmoidf_(zf0)*c0 + sigmoidf_(zi0)*tanhf_(zg0);
      c1 = sigmoidf_(zf1)*c1 + sigmoidf_(zi1)*tanhf_(zg1);
      const float h0 = sigmoidf_(zo0)*tanhf_(c0);
      const float h1 = sigmoidf_(zo1)*tanhf_(c1);
      const unsigned short h0h = f2bf(h0), h1h = f2bf(h1);
      const unsigned short h0l = f2bf(h0 - bf2f(h0h)), h1l = f2bf(h1 - bf2f(h1h));
      const unsigned whi = ((unsigned)h1h << 16) | (unsigned)h0h;
      const unsigned wlo = ((unsigned)h1l << 16) | (unsigned)h0l;
      unsigned* dst = HxOwn + ((size_t)(t & 7)*8 + g) * SLOTo;
      const int w32 = r_g*RSo + (kidx >> 1);
      __hip_atomic_store(&dst[w32],          whi, __ATOMIC_RELAXED, AGENT);
      __hip_atomic_store(&dst[16*RSo + w32], wlo, __ATOMIC_RELAXED, AGENT);
      if (hlast && t == Tlast-1){
        float2 hv{h0, h1};
        *(float2*)&hlast[(size_t)(row0 + r_g)*H + kidx] = hv;
      }
    }
    __syncthreads();   // B2: vmcnt(0)-drain per wave => h stores LLC-visible
    if (tid == 0)
      __hip_atomic_store(&flgOwn[(size_t)(g16 + m)*FSTR], (unsigned)(t+1),
                         __ATOMIC_RELAXED, AGENT);
  }

  // persist c-state (kept for protocol compatibility / future chunking)
  if (tid < NE){
    float2 cv{c0, c1};
    *(float2*)&cstate[(size_t)(row0 + r_g)*H + kidx] = cv;
  }
}

struct FusedArgs {
  const float *xs;
  const float *Wx0, *Wx1, *Wx2, *Wx3;
  const float *Wh0, *Wh1, *Wh2, *Wh3;
  const float *b0, *b1, *b2, *b3;
  unsigned *Hx0, *Hx1, *Hx2, *Hx3;
  unsigned *flags;                 // 4 layers x 128 flags x FSTR u32
  float *cst;                      // 4 x 128 x 200
  float *hlast;
  int t0, TC, Tlast;
};

// Blocks: [0,40)=L0, [40,80)=L1, [80,160)=L2, [160,240)=L3.
__global__ __launch_bounds__(256) void lstm_fused(FusedArgs a){
  extern __shared__ char smem[];
  const int b = blockIdx.x;
  constexpr int LF = 128*FSTR;     // u32 per layer's flag region
  unsigned* F = a.flags;
  if (b < 40){
    rec_stage<100, 128, 5, true>(a.xs, a.Wx0, a.Wh0, a.b0, 128,
        nullptr, a.Hx0, nullptr, F + 0*LF, F + 1*LF, 0, 5,
        a.cst + 0*128*200, nullptr, b & 7, b >> 3, a.t0, a.TC, a.Tlast, smem);
  } else if (b < 80){
    const int bb = b - 40;
    rec_stage<100, 128, 5, false>(nullptr, a.Wx1, a.Wh1, a.b1, 100,
        a.Hx0, a.Hx1, F + 0*LF, F + 1*LF, F + 2*LF, 5, 10,
        a.cst + 1*128*200, nullptr, bb & 7, bb >> 3, a.t0, a.TC, a.Tlast, smem);
  } else if (b < 160){
    const int bb = b - 80;
    rec_stage<200, 128, 10, false>(nullptr, a.Wx2, a.Wh2, a.b2, 100,
        a.Hx1, a.Hx2, F + 1*LF, F + 2*LF, F + 3*LF, 5, 10,
        a.cst + 2*128*200, nullptr, bb & 7, bb >> 3, a.t0, a.TC, a.Tlast, smem);
  } else {
    const int bb = b - 160;
    rec_stage<200, 224, 10, false>(nullptr, a.Wx3, a.Wh3, a.b3, 200,
        a.Hx2, a.Hx3, F + 2*LF, F + 3*LF, nullptr, 10, 0,
        a.cst + 3*128*200, a.hlast, bb & 7, bb >> 3, a.t0, a.TC, a.Tlast, smem);
  }
}

// ---------------------------------------------------------------------------
__global__ __launch_bounds__(256) void head_kernel(
    const float* __restrict__ hlast, const float* __restrict__ Wd,
    const float* __restrict__ bd, float* __restrict__ out)
{
  const int e = blockIdx.x*256 + threadIdx.x;
  if (e >= 128*6) return;
  const int b = e / 6, o = e - 6*b;
  float s = bd[o];
  const float* hp = hlast + (size_t)b*200;
  for (int k = 0; k < 200; ++k) s += hp[k] * Wd[k*6 + o];
  out[e] = s;
}

__global__ void fill_sentinel(float* out, int n){
  const int i = blockIdx.x*blockDim.x + threadIdx.x;
  if (i < n) out[i] = 1.0e30f;
}

// ---------------------------------------------------------------------------
extern "C" void kernel_launch(void* const* d_in, const int* in_sizes, int n_in,
                              void* d_out, int out_size, void* d_ws, size_t ws_size,
                              hipStream_t stream)
{
  (void)in_sizes; (void)n_in;
  const float* xs  = (const float*)d_in[0];
  const float* Wx[4] = {(const float*)d_in[1], (const float*)d_in[4],
                        (const float*)d_in[7], (const float*)d_in[10]};
  const float* Wh[4] = {(const float*)d_in[2], (const float*)d_in[5],
                        (const float*)d_in[8], (const float*)d_in[11]};
  const float* bs[4] = {(const float*)d_in[3], (const float*)d_in[6],
                        (const float*)d_in[9], (const float*)d_in[12]};
  const float* Wd = (const float*)d_in[13];
  const float* bd = (const float*)d_in[14];
  float* out = (float*)d_out;

  // ---- workspace layout (G0 eliminated: ~3.6 MB total) ----
  char* ws = (char*)d_ws;
  const size_t HXU[4] = {131072, 131072, 229376, 229376};   // u32 per layer
  const size_t HX_TOT = HXU[0]+HXU[1]+HXU[2]+HXU[3];
  const size_t FLAGS_BYTES = (size_t)4*128*FSTR*4;          // 128 KiB
  size_t off = 0;
  const size_t OFF_FLAGS = off; off += FLAGS_BYTES;
  const size_t OFF_HX    = off; off += HX_TOT*4;
  const size_t OFF_CST   = off; off += (size_t)4*128*200*4;
  const size_t OFF_HLAST = off; off += (size_t)128*200*4;
  off = (off + 255) & ~(size_t)255;

  if (ws_size < off){
    fill_sentinel<<<(out_size + 255)/256, 256, 0, stream>>>(out, out_size);
    return;
  }

  unsigned* flags = (unsigned*)(ws + OFF_FLAGS);
  unsigned* Hx0   = (unsigned*)(ws + OFF_HX);
  unsigned* Hx1   = Hx0 + HXU[0];
  unsigned* Hx2   = Hx1 + HXU[1];
  unsigned* Hx3   = Hx2 + HXU[2];
  float* cst      = (float*)(ws + OFF_CST);
  float* hlast    = (float*)(ws + OFF_HLAST);

  // L3 stage LDS: 2 planes * 80*456 shorts = 145920 B + zbuf 16*81*4 = 5184
  const int FUSED_LDS = 151104;
  hipFuncSetAttribute(reinterpret_cast<const void*>(lstm_fused),
                      hipFuncAttributeMaxDynamicSharedMemorySize, FUSED_LDS);

  hipMemsetAsync(flags, 0, FLAGS_BYTES, stream);
  hipMemsetAsync(Hx0, 0, HX_TOT*4, stream);

  FusedArgs fa;
  fa.xs = xs;
  fa.Wx0 = Wx[0]; fa.Wx1 = Wx[1]; fa.Wx2 = Wx[2]; fa.Wx3 = Wx[3];
  fa.Wh0 = Wh[0]; fa.Wh1 = Wh[1]; fa.Wh2 = Wh[2]; fa.Wh3 = Wh[3];
  fa.b0 = bs[0];  fa.b1 = bs[1];  fa.b2 = bs[2];  fa.b3 = bs[3];
  fa.Hx0 = Hx0; fa.Hx1 = Hx1; fa.Hx2 = Hx2; fa.Hx3 = Hx3;
  fa.flags = flags; fa.cst = cst; fa.hlast = hlast;
  fa.t0 = 0; fa.TC = 1024; fa.Tlast = 1024;

  lstm_fused<<<240, 256, FUSED_LDS, stream>>>(fa);

  head_kernel<<<3, 256, 0, stream>>>(hlast, Wd, bd, out);
}

// Round 9
// 5825.603 us; speedup vs baseline: 1.3503x; 1.0447x over previous
//
#include <hip/hip_runtime.h>
#include <cstdint>
#include <cstddef>

// ============================================================================
// 4-layer LSTM (B=128, T=1024, D=128, H={100,100,200,200}) + linear head.
// R16 = R13 (last-good, 6086us) + MONOTONIC FLAG CACHING:
//  - flags only grow, so an observation flg >= t+k licenses skipping the
//    check for k steps (visibility is sticky). Each spinning lane caches its
//    last-observed flag value; the flag load is issued only when the cache
//    is insufficient. Upstream & backpressure spins amortize ~8x (pipeline
//    skew); sibling spins (skew <= 1) save occasional reads.
//  - No scope changes, no RMWs, no protocol change: when the cache is
//    insufficient the path is byte-identical to R13. Cannot deadlock.
// R14/R15 lesson (2x verified): cross-block exchange is only correct with
// agent-scope ops on BOTH sides (LLC coherence point). Device stores bypass
// the XCD L2 without invalidating it; sc0 reads then hit stale L2 lines.
// The XCD-local-L2 exchange family is dead on this hardware.
// ============================================================================

#define AGENT __HIP_MEMORY_SCOPE_AGENT
#define FSTR 64   // u32 stride between flags (256B sector per flag)

typedef __attribute__((ext_vector_type(8))) short  short8;
typedef __attribute__((ext_vector_type(4))) float  f32x4;

__device__ __forceinline__ unsigned short f2bf(float x){
  unsigned u = __float_as_uint(x);
  unsigned r = u + 0x7FFFu + ((u >> 16) & 1u);   // RN-even to bf16
  return (unsigned short)(r >> 16);
}
__device__ __forceinline__ float bf2f(unsigned short h){
  return __uint_as_float(((unsigned)h) << 16);
}
__device__ __forceinline__ float sigmoidf_(float x){ return 1.f / (1.f + __expf(-x)); }
__device__ __forceinline__ float tanhf_(float x){
  return 1.f - 2.f / (1.f + __expf(2.f * x));
}

// spin until *p >= v; returns the last observed value (cached by caller).
__device__ __forceinline__ unsigned spin_ge(const unsigned* p, unsigned v){
  unsigned ob;
  #pragma unroll 1
  for (int i = 0; i < 32; ++i){
    ob = __hip_atomic_load(p, __ATOMIC_RELAXED, AGENT);
    if (ob >= v) return ob;
  }
  long s = 0;
  #pragma unroll 1
  while ((ob = __hip_atomic_load(p, __ATOMIC_RELAXED, AGENT)) < v){
    __builtin_amdgcn_s_sleep(8);               // ~0.2us backoff
    if (++s > (1L << 17)) break;               // fail fast on true deadlock
  }
  return ob;
}

__device__ __forceinline__ void load_hx(const unsigned* base, int w32, int loOff,
                                        short8& ah, short8& al){
  union U { unsigned long long q[2]; short8 v; } uh, ul;
  const unsigned long long* ph = (const unsigned long long*)(base + w32);
  const unsigned long long* pl = (const unsigned long long*)(base + loOff + w32);
  uh.q[0] = __hip_atomic_load(ph + 0, __ATOMIC_RELAXED, AGENT);
  uh.q[1] = __hip_atomic_load(ph + 1, __ATOMIC_RELAXED, AGENT);
  ul.q[0] = __hip_atomic_load(pl + 0, __ATOMIC_RELAXED, AGENT);
  ul.q[1] = __hip_atomic_load(pl + 1, __ATOMIC_RELAXED, AGENT);
  ah = uh.v; al = ul.v;
}

// ---------------------------------------------------------------------------
// Fused pipeline stage (window-8 h slots, per-wave two-phase waits with
// monotonic flag caching).
// XS_IN=true (layer 0): x-part from xs directly (plain cached loads).
// XS_IN=false (layers 1-3): x-part from upstream Hx slots (agent atomics).
// Hx layout per layer: [slot(8)][group(8)][plane hi/lo][16 rows][RS u32].
// Flags: index (g*16 + member) * FSTR.
// ---------------------------------------------------------------------------
template<int H, int HP, int P, bool XS_IN>
__device__ __forceinline__ void rec_stage(
    const float* __restrict__ xs,
    const float* __restrict__ Wx, const float* __restrict__ Wh,
    const float* __restrict__ bias, int HprevReal,
    const unsigned* __restrict__ HxUp, unsigned* __restrict__ HxOwn,
    const unsigned* __restrict__ flgUp, unsigned* __restrict__ flgOwn,
    unsigned* __restrict__ flgDn, int PUp, int PDn,
    float* __restrict__ cstate, float* __restrict__ hlast,
    int g, int m, int t0, int TC, int Tlast, char* smem)
{
  constexpr int HHM  = H / P;                 // 20
  constexpr int COLS = 4 * HHM;               // 80
  constexpr int ZSTR = COLS + 1;              // zbuf row stride (pad)
  constexpr int KPo  = ((H + 31)/32)*32;      // own-h padded K
  constexpr int RSo  = KPo / 2;               // own Hx row stride (u32)
  constexpr int RSp  = HP / 2;                // upstream Hx row stride
  constexpr int KX   = HP;                    // x-part K (xs D or upstream Hp)
  constexpr int KALL = KX + KPo;
  constexpr int KTX  = KX / 32;
  constexpr int KTH  = KPo / 32;
  constexpr int KSTR = KALL + 8;
  constexpr int NT   = COLS / 16;             // 5
  constexpr int NE   = 16 * HHM / 2;          // 160
  constexpr int PR   = HHM / 2;               // 10
  constexpr int N4H  = 4 * H;
  constexpr int SLOTo = 2*16*RSo;             // u32 per (slot,group), own
  constexpr int SLOTp = 2*16*RSp;             // u32 per (slot,group), upstream

  unsigned short* whT_hi = (unsigned short*)smem;
  unsigned short* whT_lo = whT_hi + COLS*KSTR;
  float* zbuf = (float*)(whT_lo + COLS*KSTR);   // [16][ZSTR]

  const int tid  = threadIdx.x;
  const int row0 = g * 16;
  const int lane = tid & 63, wave = tid >> 6;
  const int ln15 = lane & 15, quad = lane >> 4;

  // stage concatenated weight strip [col][k] = [Wx; Wh], hi/lo bf16
  for (int e = tid; e < COLS*KALL; e += 256){
    const int k = e / COLS, c = e - k*COLS;
    const int gate = c / HHM, hh = c - gate*HHM;
    const int col = gate*H + m*HHM + hh;
    float w = 0.f;
    if (k < KX){ if (k < HprevReal) w = Wx[(size_t)k*N4H + col]; }
    else { const int k2 = k - KX; if (k2 < H) w = Wh[(size_t)k2*N4H + col]; }
    const unsigned short hi = f2bf(w);
    whT_hi[c*KSTR + k] = hi;
    whT_lo[c*KSTR + k] = f2bf(w - bf2f(hi));
  }

  const int r_g  = tid / PR;
  const int hh0  = 2*(tid - r_g*PR);
  const int kidx = m*HHM + hh0;
  float c0 = 0.f, c1 = 0.f;
  if (tid < NE && t0 > 0){
    const float2 cv = *(const float2*)&cstate[(size_t)(row0 + r_g)*H + kidx];
    c0 = cv.x; c1 = cv.y;
  }
  float2 bv[4] = {};
  if (tid < NE){
    #pragma unroll
    for (int gate = 0; gate < 4; ++gate)
      bv[gate] = *(const float2*)&bias[gate*H + kidx];
  }
  __syncthreads();

  const int g16 = g*16;

  // monotonic flag caches (per participating lane)
  unsigned upC = 0, sibC = 0, dnC = 0;

  for (int tl = 0; tl < TC; ++tl){
    const int t = t0 + tl;

    // ---- phase A: per-wave upstream wait (layers 1-3), cached ----
    if constexpr (!XS_IN){
      if (lane < PUp && upC < (unsigned)(t+1))
        upC = spin_ge(&flgUp[(size_t)(g16 + lane)*FSTR], (unsigned)(t+1));
      __builtin_amdgcn_fence(__ATOMIC_ACQUIRE, "wavefront");
    }

    f32x4 acc[2];
    acc[0] = (f32x4){0.f,0.f,0.f,0.f};
    acc[1] = (f32x4){0.f,0.f,0.f,0.f};
    auto do_tile = [&](const short8& a_h, const short8& a_l, int koW){
      #pragma unroll
      for (int s = 0; s < 2; ++s){
        const int nt = wave + 4*s;
        if (nt < NT){
          const int boff = (nt*16 + ln15)*KSTR + quad*8 + koW;
          const short8 b_h = *(const short8*)&whT_hi[boff];
          const short8 b_l = *(const short8*)&whT_lo[boff];
          acc[s] = __builtin_amdgcn_mfma_f32_16x16x32_bf16(a_h, b_h, acc[s], 0,0,0);
          acc[s] = __builtin_amdgcn_mfma_f32_16x16x32_bf16(a_l, b_h, acc[s], 0,0,0);
          acc[s] = __builtin_amdgcn_mfma_f32_16x16x32_bf16(a_h, b_l, acc[s], 0,0,0);
        }
      }
    };

    // x-part MFMA: xs-direct (L0) or upstream slot (L1-3)
    if constexpr (XS_IN){
      const float* xp = xs + (size_t)(row0 + ln15)*(1024*128)
                           + (size_t)t*128 + quad*8;
      #pragma unroll
      for (int kt = 0; kt < KTX; ++kt){
        const float4 v0 = *(const float4*)(xp + kt*32);
        const float4 v1 = *(const float4*)(xp + kt*32 + 4);
        const float xv[8] = {v0.x, v0.y, v0.z, v0.w, v1.x, v1.y, v1.z, v1.w};
        union SU { unsigned short u[8]; short8 v; } sh, sl;
        #pragma unroll
        for (int j = 0; j < 8; ++j){
          const unsigned short hi = f2bf(xv[j]);
          sh.u[j] = hi;
          sl.u[j] = f2bf(xv[j] - bf2f(hi));
        }
        do_tile(sh.v, sl.v, kt*32);
      }
    } else {
      const unsigned* up = HxUp + ((size_t)(t & 7)*8 + g) * SLOTp;
      #pragma unroll
      for (int kt = 0; kt < KTX; ++kt){
        short8 a_h, a_l;
        load_hx(up, ln15*RSp + kt*16 + quad*4, 16*RSp, a_h, a_l);
        do_tile(a_h, a_l, kt*32);
      }
    }

    // ---- phase B: sibling wait (skip self) + backpressure, cached ----
    if (lane < P && lane != m && sibC < (unsigned)t)
      sibC = spin_ge(&flgOwn[(size_t)(g16 + lane)*FSTR], (unsigned)t);
    if (PDn > 0 && t >= 8 && lane >= 40 && lane < 40 + PDn
        && dnC < (unsigned)(t-7))
      dnC = spin_ge(&flgDn[(size_t)(g16 + (lane-40))*FSTR], (unsigned)(t-7));
    __builtin_amdgcn_fence(__ATOMIC_ACQUIRE, "wavefront");

    {
      const unsigned* own = HxOwn + ((size_t)((t-1) & 7)*8 + g) * SLOTo;
      #pragma unroll
      for (int kt = 0; kt < KTH; ++kt){
        short8 a_h, a_l;
        load_hx(own, ln15*RSo + kt*16 + quad*4, 16*RSo, a_h, a_l);
        do_tile(a_h, a_l, KX + kt*32);
      }
    }
    {
      #pragma unroll
      for (int s = 0; s < 2; ++s){
        const int nt = wave + 4*s;
        if (nt < NT)
          #pragma unroll
          for (int r = 0; r < 4; ++r)
            zbuf[(quad*4 + r)*ZSTR + nt*16 + ln15] = acc[s][r];
      }
    }
    __syncthreads();   // B1: zbuf ready

    // gates + state update + publish h_t -> own slot t&7
    if (tid < NE){
      const float* zr = zbuf + r_g*ZSTR;
      const float zi0 = zr[0*HHM + hh0]   + bv[0].x, zi1 = zr[0*HHM + hh0+1] + bv[0].y;
      const float zf0 = zr[1*HHM + hh0]   + bv[1].x, zf1 = zr[1*HHM + hh0+1] + bv[1].y;
      const float zg0 = zr[2*HHM + hh0]   + bv[2].x, zg1 = zr[2*HHM + hh0+1] + bv[2].y;
      const float zo0 = zr[3*HHM + hh0]   + bv[3].x, zo1 = zr[3*HHM + hh0+1] + bv[3].y;
      c0 = sigmoidf_(zf0)*c0 + sigmoidf_(zi0)*tanhf_(zg0);
      c1 = sigmoidf_(zf1)*c1 + sigmoidf_(zi1)*tanhf_(zg1);
      const float h0 = sigmoidf_(zo0)*tanhf_(c0);
      const float h1 = sigmoidf_(zo1)*tanhf_(c1);
      const unsigned short h0h = f2bf(h0), h1h = f2bf(h1);
      const unsigned short h0l = f2bf(h0 - bf2f(h0h)), h1l = f2bf(h1 - bf2f(h1h));
      const unsigned whi = ((unsigned)h1h << 16) | (unsigned)h0h;
      const unsigned wlo = ((unsigned)h1l << 16) | (unsigned)h0l;
      unsigned* dst = HxOwn + ((size_t)(t & 7)*8 + g) * SLOTo;
      const int w32 = r_g*RSo + (kidx >> 1);
      __hip_atomic_store(&dst[w32],          whi, __ATOMIC_RELAXED, AGENT);
      __hip_atomic_store(&dst[16*RSo + w32], wlo, __ATOMIC_RELAXED, AGENT);
      if (hlast && t == Tlast-1){
        float2 hv{h0, h1};
        *(float2*)&hlast[(size_t)(row0 + r_g)*H + kidx] = hv;
      }
    }
    __syncthreads();   // B2: vmcnt(0)-drain per wave => h stores LLC-visible
    if (tid == 0)
      __hip_atomic_store(&flgOwn[(size_t)(g16 + m)*FSTR], (unsigned)(t+1),
                         __ATOMIC_RELAXED, AGENT);
  }

  // persist c-state
  if (tid < NE){
    float2 cv{c0, c1};
    *(float2*)&cstate[(size_t)(row0 + r_g)*H + kidx] = cv;
  }
}

struct FusedArgs {
  const float *xs;
  const float *Wx0, *Wx1, *Wx2, *Wx3;
  const float *Wh0, *Wh1, *Wh2, *Wh3;
  const float *b0, *b1, *b2, *b3;
  unsigned *Hx0, *Hx1, *Hx2, *Hx3;
  unsigned *flags;                 // 4 layers x 128 flags x FSTR u32
  float *cst;                      // 4 x 128 x 200
  float *hlast;
  int t0, TC, Tlast;
};

// Blocks: [0,40)=L0, [40,80)=L1, [80,160)=L2, [160,240)=L3.
__global__ __launch_bounds__(256) void lstm_fused(FusedArgs a){
  extern __shared__ char smem[];
  const int b = blockIdx.x;
  constexpr int LF = 128*FSTR;     // u32 per layer's flag region
  unsigned* F = a.flags;
  if (b < 40){
    rec_stage<100, 128, 5, true>(a.xs, a.Wx0, a.Wh0, a.b0, 128,
        nullptr, a.Hx0, nullptr, F + 0*LF, F + 1*LF, 0, 5,
        a.cst + 0*128*200, nullptr, b & 7, b >> 3, a.t0, a.TC, a.Tlast, smem);
  } else if (b < 80){
    const int bb = b - 40;
    rec_stage<100, 128, 5, false>(nullptr, a.Wx1, a.Wh1, a.b1, 100,
        a.Hx0, a.Hx1, F + 0*LF, F + 1*LF, F + 2*LF, 5, 10,
        a.cst + 1*128*200, nullptr, bb & 7, bb >> 3, a.t0, a.TC, a.Tlast, smem);
  } else if (b < 160){
    const int bb = b - 80;
    rec_stage<200, 128, 10, false>(nullptr, a.Wx2, a.Wh2, a.b2, 100,
        a.Hx1, a.Hx2, F + 1*LF, F + 2*LF, F + 3*LF, 5, 10,
        a.cst + 2*128*200, nullptr, bb & 7, bb >> 3, a.t0, a.TC, a.Tlast, smem);
  } else {
    const int bb = b - 160;
    rec_stage<200, 224, 10, false>(nullptr, a.Wx3, a.Wh3, a.b3, 200,
        a.Hx2, a.Hx3, F + 2*LF, F + 3*LF, nullptr, 10, 0,
        a.cst + 3*128*200, a.hlast, bb & 7, bb >> 3, a.t0, a.TC, a.Tlast, smem);
  }
}

// ---------------------------------------------------------------------------
__global__ __launch_bounds__(256) void head_kernel(
    const float* __restrict__ hlast, const float* __restrict__ Wd,
    const float* __restrict__ bd, float* __restrict__ out)
{
  const int e = blockIdx.x*256 + threadIdx.x;
  if (e >= 128*6) return;
  const int b = e / 6, o = e - 6*b;
  float s = bd[o];
  const float* hp = hlast + (size_t)b*200;
  for (int k = 0; k < 200; ++k) s += hp[k] * Wd[k*6 + o];
  out[e] = s;
}

__global__ void fill_sentinel(float* out, int n){
  const int i = blockIdx.x*blockDim.x + threadIdx.x;
  if (i < n) out[i] = 1.0e30f;
}

// ---------------------------------------------------------------------------
extern "C" void kernel_launch(void* const* d_in, const int* in_sizes, int n_in,
                              void* d_out, int out_size, void* d_ws, size_t ws_size,
                              hipStream_t stream)
{
  (void)in_sizes; (void)n_in;
  const float* xs  = (const float*)d_in[0];
  const float* Wx[4] = {(const float*)d_in[1], (const float*)d_in[4],
                        (const float*)d_in[7], (const float*)d_in[10]};
  const float* Wh[4] = {(const float*)d_in[2], (const float*)d_in[5],
                        (const float*)d_in[8], (const float*)d_in[11]};
  const float* bs[4] = {(const float*)d_in[3], (const float*)d_in[6],
                        (const float*)d_in[9], (const float*)d_in[12]};
  const float* Wd = (const float*)d_in[13];
  const float* bd = (const float*)d_in[14];
  float* out = (float*)d_out;

  // ---- workspace layout ----
  char* ws = (char*)d_ws;
  const size_t HXU[4] = {131072, 131072, 229376, 229376};   // u32 per layer
  const size_t HX_TOT = HXU[0]+HXU[1]+HXU[2]+HXU[3];
  const size_t FLAGS_BYTES = (size_t)4*128*FSTR*4;          // 128 KiB
  size_t off = 0;
  const size_t OFF_FLAGS = off; off += FLAGS_BYTES;
  const size_t OFF_HX    = off; off += HX_TOT*4;
  const size_t OFF_CST   = off; off += (size_t)4*128*200*4;
  const size_t OFF_HLAST = off; off += (size_t)128*200*4;
  off = (off + 255) & ~(size_t)255;

  if (ws_size < off){
    fill_sentinel<<<(out_size + 255)/256, 256, 0, stream>>>(out, out_size);
    return;
  }

  unsigned* flags = (unsigned*)(ws + OFF_FLAGS);
  unsigned* Hx0   = (unsigned*)(ws + OFF_HX);
  unsigned* Hx1   = Hx0 + HXU[0];
  unsigned* Hx2   = Hx1 + HXU[1];
  unsigned* Hx3   = Hx2 + HXU[2];
  float* cst      = (float*)(ws + OFF_CST);
  float* hlast    = (float*)(ws + OFF_HLAST);

  // L3 stage LDS: 2 planes * 80*456 shorts = 145920 B + zbuf 16*81*4 = 5184
  const int FUSED_LDS = 151104;
  hipFuncSetAttribute(reinterpret_cast<const void*>(lstm_fused),
                      hipFuncAttributeMaxDynamicSharedMemorySize, FUSED_LDS);

  hipMemsetAsync(flags, 0, FLAGS_BYTES, stream);
  hipMemsetAsync(Hx0, 0, HX_TOT*4, stream);

  FusedArgs fa;
  fa.xs = xs;
  fa.Wx0 = Wx[0]; fa.Wx1 = Wx[1]; fa.Wx2 = Wx[2]; fa.Wx3 = Wx[3];
  fa.Wh0 = Wh[0]; fa.Wh1 = Wh[1]; fa.Wh2 = Wh[2]; fa.Wh3 = Wh[3];
  fa.b0 = bs[0];  fa.b1 = bs[1];  fa.b2 = bs[2];  fa.b3 = bs[3];
  fa.Hx0 = Hx0; fa.Hx1 = Hx1; fa.Hx2 = Hx2; fa.Hx3 = Hx3;
  fa.flags = flags; fa.cst = cst; fa.hlast = hlast;
  fa.t0 = 0; fa.TC = 1024; fa.Tlast = 1024;

  lstm_fused<<<240, 256, FUSED_LDS, stream>>>(fa);

  head_kernel<<<3, 256, 0, stream>>>(hlast, Wd, bd, out);
}